// Round 3
// baseline (81.234 us; speedup 1.0000x reference)
//
#include <hip/hip_runtime.h>
#include <hip/hip_bf16.h>
#include <math.h>

#define N_ROWS 4096
#define D_DIM  128
#define M_ROWS 8192
#define INV_T  10.0f
// sqrt(10/ln2): zn scaled so Gram(zn) = 10*log2(e)*cos  =>  exp2(Gram) = e^(10*cos)
#define BF_SCALE 3.79828218f

#if __has_builtin(__builtin_amdgcn_exp2f)
#define EXP2(x) __builtin_amdgcn_exp2f(x)   // bare v_exp_f32, no OCML fixup
#else
#define EXP2(x) exp2f(x)
#endif

typedef __attribute__((ext_vector_type(8))) short bf16x8;
typedef __attribute__((ext_vector_type(4))) float f32x4;

// --- Kernel 1: fused normalize (scaled bf16) + pos + zero S + zero out ---
__global__ __launch_bounds__(256) void prep_kernel(
    const float* __restrict__ z1, const float* __restrict__ z2,
    ushort* __restrict__ zn, float* __restrict__ pos,
    float* __restrict__ S, float* __restrict__ out)
{
    if (blockIdx.x < 32) S[blockIdx.x * 256 + threadIdx.x] = 0.f;
    if (blockIdx.x == 32 && threadIdx.x == 0) out[0] = 0.f;

    const int i    = blockIdx.x * 4 + (threadIdx.x >> 6);
    const int lane = threadIdx.x & 63;
    float2 a = ((const float2*)(z1 + (size_t)i * D_DIM))[lane];
    float2 b = ((const float2*)(z2 + (size_t)i * D_DIM))[lane];
    float s11 = a.x * a.x + a.y * a.y;
    float s22 = b.x * b.x + b.y * b.y;
    float s12 = a.x * b.x + a.y * b.y;
    #pragma unroll
    for (int m = 1; m < 64; m <<= 1) {
        s11 += __shfl_xor(s11, m, 64);
        s22 += __shfl_xor(s22, m, 64);
        s12 += __shfl_xor(s12, m, 64);
    }
    float inv1 = 1.0f / fmaxf(sqrtf(s11), 1e-8f);
    float inv2 = 1.0f / fmaxf(sqrtf(s22), 1e-8f);
    if (lane == 0) pos[i] = 2.0f * INV_T * s12 * inv1 * inv2;
    const float sa = inv1 * BF_SCALE, sb = inv2 * BF_SCALE;
    __hip_bfloat16 h;
    ushort2 oa, ob;
    h = __float2bfloat16(a.x * sa); oa.x = *(const ushort*)&h;
    h = __float2bfloat16(a.y * sa); oa.y = *(const ushort*)&h;
    h = __float2bfloat16(b.x * sb); ob.x = *(const ushort*)&h;
    h = __float2bfloat16(b.y * sb); ob.y = *(const ushort*)&h;
    ((ushort2*)zn)[(size_t)i * 64 + lane] = oa;
    ((ushort2*)zn)[(size_t)(i + N_ROWS) * 64 + lane] = ob;
}

// --- Kernel 2: symmetric simsum (R0 structure: fire-and-forget S atomics,
// ONE barrier) + anti-diagonal PAIRING. Blocks along an anti-diagonal share
// the column tile: cU=(rU+bx)&63 is constant for (bx,rU),(bx+1,rU-1). Grid is
// (p,t) in 17x64 with t==cU: each block stages column tile t ONCE (32 KiB
// LDS, XOR-swizzled), then sequentially processes TWO row tiles bx=2p,2p+1
// (p==16 handles the lone bx=32, active iff t>=32). 2080 tile-passes in 1056
// blocks => all resident in one scheduling round (5 blocks/CU by LDS), no
// tail; staging traffic halved. Pass loop is unroll(1) so only one afrag set
// is live => VGPR ~= R0. R1/R2 lessons: atomics stay fire-and-forget (no
// trailing sync, no privatization).
__global__ __launch_bounds__(256) void simsum_kernel(
    const short* __restrict__ zn, float* __restrict__ S)
{
    const int p = blockIdx.x;           // 0..16
    const int t = blockIdx.y;           // 0..63 == cU
    if (p == 16 && t < 32) return;      // bx=32 exists only for rU<32 <=> t>=32
    const int npass = (p == 16) ? 1 : 2;

    __shared__ uint4 lbuf[128 * 16];    // 32 KiB exactly: [row][chunk]

    const int tid  = threadIdx.x;
    const int lane = tid & 63;
    const int w    = tid >> 6;
    const int m    = lane & 15;
    const int q    = lane >> 4;
    const int colBase = t * 128;

    // Stage the whole 128 x 256B col tile: 8 uint4 per thread, coalesced.
    // Rows sr+16j => row&15 == sr, so swizzled chunk sc^sr is constant.
    {
        const int sr = tid >> 4;
        const int sc = tid & 15;
        const uint4* gsrc = (const uint4*)(zn + (size_t)(colBase + sr) * D_DIM) + sc;
        const int swc = sc ^ sr;
        uint4 regs[8];
        #pragma unroll
        for (int j = 0; j < 8; ++j) regs[j] = gsrc[j * 256];   // 16 rows apart
        #pragma unroll
        for (int j = 0; j < 8; ++j) lbuf[(sr + j * 16) * 16 + swc] = regs[j];
    }

    __syncthreads();   // the ONLY barrier in this kernel
    const short* lb = (const short*)lbuf;

    #pragma unroll 1   // keep ONE afrag set live (VGPR), no cross-pass hoist
    for (int pass = 0; pass < npass; ++pass) {
        const int bxp = 2 * p + pass;           // 0..32
        const int rUp = (t - bxp) & 63;
        const bool isDiag = (bxp == 0);
        const int rowBase = rUp * 128 + w * 32;

        // A fragments: 2 row-sets x 4 K-steps, registers for this pass
        bf16x8 afrag[2][4];
        #pragma unroll
        for (int h = 0; h < 2; ++h) {
            const short* ar = zn + (size_t)(rowBase + h * 16 + m) * D_DIM + q * 8;
            #pragma unroll
            for (int s = 0; s < 4; ++s) afrag[h][s] = *(const bf16x8*)(ar + s * 32);
        }

        float rsum[8] = {0.f, 0.f, 0.f, 0.f, 0.f, 0.f, 0.f, 0.f};

        #pragma unroll 2
        for (int ct = 0; ct < 8; ++ct) {
            f32x4 acc0 = {0.f, 0.f, 0.f, 0.f};
            f32x4 acc1 = {0.f, 0.f, 0.f, 0.f};
            #pragma unroll
            for (int s = 0; s < 4; ++s) {
                bf16x8 bfrag = *(const bf16x8*)(lb + (ct * 16 + m) * D_DIM
                                                + (((q + s * 4) ^ m) * 8));
                acc0 = __builtin_amdgcn_mfma_f32_16x16x32_bf16(afrag[0][s], bfrag, acc0, 0, 0, 0);
                acc1 = __builtin_amdgcn_mfma_f32_16x16x32_bf16(afrag[1][s], bfrag, acc1, 0, 0, 0);
            }
            const int tileCol = colBase + ct * 16;
            float e0[4], e1[4];
            #pragma unroll
            for (int r = 0; r < 4; ++r) { e0[r] = EXP2(acc0[r]); e1[r] = EXP2(acc1[r]); }
            // diagonal mask: wave-uniform branches; fire only when rUp == t
            if (tileCol == rowBase) {
                #pragma unroll
                for (int r = 0; r < 4; ++r) if (m == q * 4 + r) e0[r] = 0.f;
            }
            if (tileCol == rowBase + 16) {
                #pragma unroll
                for (int r = 0; r < 4; ++r) if (m == q * 4 + r) e1[r] = 0.f;
            }
            #pragma unroll
            for (int r = 0; r < 4; ++r) { rsum[r] += e0[r]; rsum[4 + r] += e1[r]; }
            // column partial for col (tileCol + m) over this wave's 32 rows:
            // straight to S via atomics (fire-and-forget, no dependents)
            if (!isDiag) {
                float cs = (e0[0] + e0[1]) + (e0[2] + e0[3])
                         + (e1[0] + e1[1]) + (e1[2] + e1[3]);
                cs += __shfl_xor(cs, 16, 64);
                cs += __shfl_xor(cs, 32, 64);
                if (q == 0) atomicAdd(&S[tileCol + m], cs);
            }
        }

        // row sums -> S[row]
        #pragma unroll
        for (int msk = 1; msk < 16; msk <<= 1) {
            #pragma unroll
            for (int r = 0; r < 8; ++r) rsum[r] += __shfl_xor(rsum[r], msk, 64);
        }
        if (m < 4) {
            atomicAdd(&S[rowBase + q * 4 + m],      rsum[m]);
            atomicAdd(&S[rowBase + 16 + q * 4 + m], rsum[4 + m]);
        }
    }
}

// --- Kernel 3: out += (1/M^2) * sum_i [ log(S_i + exp(pos_i)) - pos_i ] ---
__global__ __launch_bounds__(1024) void loss_kernel(
    const float* __restrict__ S, const float* __restrict__ pos,
    float* __restrict__ out)
{
    const int i = blockIdx.x * 1024 + threadIdx.x;
    float p = pos[i & (N_ROWS - 1)];
    float v = __logf(S[i] + __expf(p)) - p;
    #pragma unroll
    for (int msk = 1; msk < 64; msk <<= 1) v += __shfl_xor(v, msk, 64);
    __shared__ float red[16];
    if ((threadIdx.x & 63) == 0) red[threadIdx.x >> 6] = v;
    __syncthreads();
    if (threadIdx.x == 0) {
        float tsum = 0.f;
        #pragma unroll
        for (int wv = 0; wv < 16; ++wv) tsum += red[wv];
        atomicAdd(out, tsum * (1.0f / ((float)M_ROWS * (float)M_ROWS)));
    }
}

extern "C" void kernel_launch(void* const* d_in, const int* in_sizes, int n_in,
                              void* d_out, int out_size, void* d_ws, size_t ws_size,
                              hipStream_t stream)
{
    const float* z1 = (const float*)d_in[0];
    const float* z2 = (const float*)d_in[1];
    float* out = (float*)d_out;

    char* wsp = (char*)d_ws;
    short* zn  = (short*)(wsp);                    // 2 MiB
    float* pos = (float*)(wsp + 2097152);          // 16 KiB
    float* S   = (float*)(wsp + 2097152 + 16384);  // 32 KiB

    prep_kernel<<<N_ROWS / 4, 256, 0, stream>>>(z1, z2, (ushort*)zn, pos, S, out);
    simsum_kernel<<<dim3(17, 64), 256, 0, stream>>>(zn, S);
    loss_kernel<<<M_ROWS / 1024, 1024, 0, stream>>>(S, pos, out);
}

// Round 4
// 78.586 us; speedup vs baseline: 1.0337x; 1.0337x over previous
//
#include <hip/hip_runtime.h>
#include <hip/hip_bf16.h>
#include <math.h>

#define N_ROWS 4096
#define D_DIM  128
#define M_ROWS 8192
#define INV_T  10.0f
// sqrt(10/ln2): zn scaled so Gram(zn) = 10*log2(e)*cos  =>  exp2(Gram) = e^(10*cos)
#define BF_SCALE 3.79828218f

#if __has_builtin(__builtin_amdgcn_exp2f)
#define EXP2(x) __builtin_amdgcn_exp2f(x)   // bare v_exp_f32, no OCML fixup
#else
#define EXP2(x) exp2f(x)
#endif

typedef __attribute__((ext_vector_type(8))) short bf16x8;
typedef __attribute__((ext_vector_type(4))) float f32x4;

// --- Kernel 1: fused normalize (scaled bf16) + pos + zero S + zero out ---
__global__ __launch_bounds__(256) void prep_kernel(
    const float* __restrict__ z1, const float* __restrict__ z2,
    ushort* __restrict__ zn, float* __restrict__ pos,
    float* __restrict__ S, float* __restrict__ out)
{
    if (blockIdx.x < 32) S[blockIdx.x * 256 + threadIdx.x] = 0.f;
    if (blockIdx.x == 32 && threadIdx.x == 0) out[0] = 0.f;

    const int i    = blockIdx.x * 4 + (threadIdx.x >> 6);
    const int lane = threadIdx.x & 63;
    float2 a = ((const float2*)(z1 + (size_t)i * D_DIM))[lane];
    float2 b = ((const float2*)(z2 + (size_t)i * D_DIM))[lane];
    float s11 = a.x * a.x + a.y * a.y;
    float s22 = b.x * b.x + b.y * b.y;
    float s12 = a.x * b.x + a.y * b.y;
    #pragma unroll
    for (int m = 1; m < 64; m <<= 1) {
        s11 += __shfl_xor(s11, m, 64);
        s22 += __shfl_xor(s22, m, 64);
        s12 += __shfl_xor(s12, m, 64);
    }
    float inv1 = 1.0f / fmaxf(sqrtf(s11), 1e-8f);
    float inv2 = 1.0f / fmaxf(sqrtf(s22), 1e-8f);
    if (lane == 0) pos[i] = 2.0f * INV_T * s12 * inv1 * inv2;
    const float sa = inv1 * BF_SCALE, sb = inv2 * BF_SCALE;
    __hip_bfloat16 h;
    ushort2 oa, ob;
    h = __float2bfloat16(a.x * sa); oa.x = *(const ushort*)&h;
    h = __float2bfloat16(a.y * sa); oa.y = *(const ushort*)&h;
    h = __float2bfloat16(b.x * sb); ob.x = *(const ushort*)&h;
    h = __float2bfloat16(b.y * sb); ob.y = *(const ushort*)&h;
    ((ushort2*)zn)[(size_t)i * 64 + lane] = oa;
    ((ushort2*)zn)[(size_t)(i + N_ROWS) * 64 + lane] = ob;
}

// --- Kernel 2: symmetric simsum. E = exp(sim) is symmetric: only the upper
// triangle of 128x128 unit tiles is computed. Wrapped-diagonal grid: (bx,rU)
// in 33x64, cU=(rU+bx)&63, bx==32 only for rU<32 => each unordered pair once
// (2080 blocks). One-shot staging (whole 128-col tile -> 32 KiB LDS,
// XOR-swizzled), ONE barrier total. Column sums go straight to S[col] via
// per-wave atomics (no colpart LDS, no second barrier) => LDS exactly 32 KiB
// => 5 blocks/CU. NO device fences anywhere (R10 lesson). R1-R3 lessons:
// fire-and-forget atomics are free (R1: waiting on them cost +16 us);
// privatization (R2) and anti-diagonal pairing (R3) both regressed.
__global__ __launch_bounds__(256) void simsum_kernel(
    const short* __restrict__ zn, float* __restrict__ S)
{
    const int bx = blockIdx.x;          // 0..32
    const int rU = blockIdx.y;          // 0..63
    if (bx == 32 && rU >= 32) return;   // distance-32 pairs covered once
    const int cU = (rU + bx) & 63;
    const bool isDiag = (bx == 0);

    __shared__ uint4 lbuf[128 * 16];    // 32 KiB exactly: [row][chunk]

    const int tid  = threadIdx.x;
    const int lane = tid & 63;
    const int w    = tid >> 6;
    const int m    = lane & 15;
    const int q    = lane >> 4;
    const int rowBase = rU * 128 + w * 32;
    const int colBase = cU * 128;

    // Stage the whole 128 x 256B col tile: 8 uint4 per thread, coalesced.
    // Rows sr+16j => row&15 == sr, so swizzled chunk sc^sr is constant.
    {
        const int sr = tid >> 4;
        const int sc = tid & 15;
        const uint4* gsrc = (const uint4*)(zn + (size_t)(colBase + sr) * D_DIM) + sc;
        const int swc = sc ^ sr;
        uint4 regs[8];
        #pragma unroll
        for (int j = 0; j < 8; ++j) regs[j] = gsrc[j * 256];   // 16 rows apart
        #pragma unroll
        for (int j = 0; j < 8; ++j) lbuf[(sr + j * 16) * 16 + swc] = regs[j];
    }

    // A fragments: 2 row-sets x 4 K-steps, registers for the whole kernel
    bf16x8 afrag[2][4];
    #pragma unroll
    for (int h = 0; h < 2; ++h) {
        const short* ar = zn + (size_t)(rowBase + h * 16 + m) * D_DIM + q * 8;
        #pragma unroll
        for (int s = 0; s < 4; ++s) afrag[h][s] = *(const bf16x8*)(ar + s * 32);
    }

    __syncthreads();   // the ONLY barrier in this kernel

    float rsum[8] = {0.f, 0.f, 0.f, 0.f, 0.f, 0.f, 0.f, 0.f};
    const short* lb = (const short*)lbuf;

    #pragma unroll 2
    for (int ct = 0; ct < 8; ++ct) {
        f32x4 acc0 = {0.f, 0.f, 0.f, 0.f};
        f32x4 acc1 = {0.f, 0.f, 0.f, 0.f};
        #pragma unroll
        for (int s = 0; s < 4; ++s) {
            bf16x8 bfrag = *(const bf16x8*)(lb + (ct * 16 + m) * D_DIM
                                            + (((q + s * 4) ^ m) * 8));
            acc0 = __builtin_amdgcn_mfma_f32_16x16x32_bf16(afrag[0][s], bfrag, acc0, 0, 0, 0);
            acc1 = __builtin_amdgcn_mfma_f32_16x16x32_bf16(afrag[1][s], bfrag, acc1, 0, 0, 0);
        }
        const int tileCol = colBase + ct * 16;
        float e0[4], e1[4];
        #pragma unroll
        for (int r = 0; r < 4; ++r) { e0[r] = EXP2(acc0[r]); e1[r] = EXP2(acc1[r]); }
        // diagonal mask: wave-uniform branches; fire only when rU == cU
        if (tileCol == rowBase) {
            #pragma unroll
            for (int r = 0; r < 4; ++r) if (m == q * 4 + r) e0[r] = 0.f;
        }
        if (tileCol == rowBase + 16) {
            #pragma unroll
            for (int r = 0; r < 4; ++r) if (m == q * 4 + r) e1[r] = 0.f;
        }
        #pragma unroll
        for (int r = 0; r < 4; ++r) { rsum[r] += e0[r]; rsum[4 + r] += e1[r]; }
        // column partial for col (tileCol + m) over this wave's 32 rows:
        // straight to S via atomics (fire-and-forget, no dependents)
        if (!isDiag) {
            float cs = (e0[0] + e0[1]) + (e0[2] + e0[3])
                     + (e1[0] + e1[1]) + (e1[2] + e1[3]);
            cs += __shfl_xor(cs, 16, 64);
            cs += __shfl_xor(cs, 32, 64);
            if (q == 0) atomicAdd(&S[tileCol + m], cs);
        }
    }

    // row sums -> S[row]
    #pragma unroll
    for (int msk = 1; msk < 16; msk <<= 1) {
        #pragma unroll
        for (int r = 0; r < 8; ++r) rsum[r] += __shfl_xor(rsum[r], msk, 64);
    }
    if (m < 4) {
        atomicAdd(&S[rowBase + q * 4 + m],      rsum[m]);
        atomicAdd(&S[rowBase + 16 + q * 4 + m], rsum[4 + m]);
    }
}

// --- Kernel 3: out += (1/M^2) * sum_i [ log(S_i + exp(pos_i)) - pos_i ] ---
__global__ __launch_bounds__(1024) void loss_kernel(
    const float* __restrict__ S, const float* __restrict__ pos,
    float* __restrict__ out)
{
    const int i = blockIdx.x * 1024 + threadIdx.x;
    float p = pos[i & (N_ROWS - 1)];
    float v = __logf(S[i] + __expf(p)) - p;
    #pragma unroll
    for (int msk = 1; msk < 64; msk <<= 1) v += __shfl_xor(v, msk, 64);
    __shared__ float red[16];
    if ((threadIdx.x & 63) == 0) red[threadIdx.x >> 6] = v;
    __syncthreads();
    if (threadIdx.x == 0) {
        float t = 0.f;
        #pragma unroll
        for (int wv = 0; wv < 16; ++wv) t += red[wv];
        atomicAdd(out, t * (1.0f / ((float)M_ROWS * (float)M_ROWS)));
    }
}

extern "C" void kernel_launch(void* const* d_in, const int* in_sizes, int n_in,
                              void* d_out, int out_size, void* d_ws, size_t ws_size,
                              hipStream_t stream)
{
    const float* z1 = (const float*)d_in[0];
    const float* z2 = (const float*)d_in[1];
    float* out = (float*)d_out;

    char* wsp = (char*)d_ws;
    short* zn  = (short*)(wsp);                    // 2 MiB
    float* pos = (float*)(wsp + 2097152);          // 16 KiB
    float* S   = (float*)(wsp + 2097152 + 16384);  // 32 KiB

    prep_kernel<<<N_ROWS / 4, 256, 0, stream>>>(z1, z2, (ushort*)zn, pos, S, out);
    simsum_kernel<<<dim3(33, 64), 256, 0, stream>>>(zn, S);
    loss_kernel<<<M_ROWS / 1024, 1024, 0, stream>>>(S, pos, out);
}